// Round 9
// baseline (357.059 us; speedup 1.0000x reference)
//
#include <hip/hip_runtime.h>
#include <hip/hip_bf16.h>

#define Bsz 4
#define Lsz 2048
#define Hsz 8

typedef __attribute__((ext_vector_type(8)))  short bf16x8;
typedef __attribute__((ext_vector_type(4)))  short bf16x4;
typedef __attribute__((ext_vector_type(4)))  float f32x4;

__device__ __forceinline__ short f2bs(float f) {   // RNE (same converter prep_kv used)
    union { float f; unsigned u; } v; v.f = f;
    unsigned r = v.u + 0x7FFFu + ((v.u >> 16) & 1u);
    return (short)(r >> 16);
}
__device__ __forceinline__ short f2bs_rh(float f) { // round-half-up, 2 ops (P pack)
    return (short)((__float_as_uint(f) + 0x8000u) >> 16);
}

// ---------------- single fused kernel: NO prep pass, NO workspace ----------------
// R8 proved the fused structure correct (scalar f2bs, L2 absorbs fp32 K/V re-reads:
// FETCH 28.5MB, no spill) but ran 72us with all pipes <31% busy: tile t's K/V
// loads were issued IN tile t's body -> ~300cyc exposed L2 latency every tile.
// R9: register double-buffer prefetch (T14). Tile t+1's fp32 K (4x float4) and V
// (16 dwords) are loaded into the OTHER register bank at the top of body t; the
// load latency hides under body t's full compute (~600+ cyc). Banks are
// compile-time (A/B token-pasted, loop unrolled x2) - rule #20. +32 VGPR -> ~116,
// under the (256,3) ~170 cap. Also qt = 31-y: longest chains dispatched first
// (LPT) for a shorter tail at 3 blocks/CU.
// LDS: dls 8K + Qs 8K + Ored 32K = 48 KB -> 3 blocks/CU, 12 waves/CU.
__global__ __launch_bounds__(256, 3) void dsattn_fused(
    const float* __restrict__ q,
    const float* __restrict__ ksrc,
    const float* __restrict__ vsrc,
    const float* __restrict__ tau,
    const float* __restrict__ delta,
    float* __restrict__ out)
{
    __shared__ float dls[Lsz];                       //  8 KB c2*delta[b][:]
    __shared__ __align__(16) short Qs[4096];         //  8 KB Q frags
    __shared__ __align__(16) float Ored[2][4096];    // 32 KB epilogue overlay

    const int tid  = threadIdx.x;
    const int kq   = tid >> 6;        // wave id == key-quarter
    const int lane = tid & 63;
    const int ln   = lane & 15;
    const int quad = lane >> 4;

    const int bh = blockIdx.x;
    const int b  = bh >> 3, h = bh & 7;
    const int qt = 31 - blockIdx.y;   // descending chain length (LPT dispatch)
    const int q0 = qt * 64;
    const int T  = qt + 1;            // 64-key tiles

    const float c2  = 0.125f * 1.44269504f;   // scale * log2(e)
    const float st2 = c2 * tau[b];

    // stage c2*delta (256 thr x 8 floats) - prologue only
    {
        const float* dsrc = delta + (size_t)b*Lsz + tid*8;
        float4 av = *(const float4*)(dsrc);
        float4 cv = *(const float4*)(dsrc + 4);
        av.x*=c2; av.y*=c2; av.z*=c2; av.w*=c2;
        cv.x*=c2; cv.y*=c2; cv.z*=c2; cv.w*=c2;
        *(float4*)&dls[tid*8]     = av;
        *(float4*)&dls[tid*8 + 4] = cv;
    }

    // Q frags -> LDS (wave kq builds q-group qg=kq; B-operand of 16x16x32)
    {
        const float* qrow = q + (((size_t)b*Lsz + q0 + kq*16 + ln)*Hsz + h)*64;
        float4 a0 = *(const float4*)(qrow + quad*8);
        float4 a1 = *(const float4*)(qrow + quad*8 + 4);
        float4 b0 = *(const float4*)(qrow + 32 + quad*8);
        float4 b1 = *(const float4*)(qrow + 32 + quad*8 + 4);
        bf16x8 q0f = {f2bs(a0.x),f2bs(a0.y),f2bs(a0.z),f2bs(a0.w),
                      f2bs(a1.x),f2bs(a1.y),f2bs(a1.z),f2bs(a1.w)};
        bf16x8 q1f = {f2bs(b0.x),f2bs(b0.y),f2bs(b0.z),f2bs(b0.w),
                      f2bs(b1.x),f2bs(b1.y),f2bs(b1.z),f2bs(b1.w)};
        *(bf16x8*)(&Qs[(kq*2+0)*512 + lane*8]) = q0f;
        *(bf16x8*)(&Qs[(kq*2+1)*512 + lane*8]) = q1f;
    }

    // per-wave fp32 source pointers; tile stride = 64 rows = 32768 floats
    // K lane: row kq*16+ln, cols [quad*8,+8) and [32+quad*8,+8)
    const float* kp = ksrc + (((size_t)b*Lsz + kq*16 + ln)*Hsz + h)*64 + quad*8;
    // V lane: rows kq*16+quad*4+j (j=0..3, +j*512), col dg*16+ln (+dg*16)
    const float* vp = vsrc + (((size_t)b*Lsz + kq*16 + quad*4)*Hsz + h)*64 + ln;

    f32x4 oacc[4][4];                 // [dg][qg]; O[q=qg*16+ln][d=dg*16+quad*4+i]
    #pragma unroll
    for (int dg = 0; dg < 4; ++dg)
        #pragma unroll
        for (int qg = 0; qg < 4; ++qg)
            oacc[dg][qg] = (f32x4){0.f,0.f,0.f,0.f};
    float l_acc[4] = {0.f,0.f,0.f,0.f};

    // ---- two register banks for the K/V fp32 double buffer ----
    float4 Aka0, Aka1, Akb0, Akb1; float Avs[16];
    float4 Bka0, Bka1, Bkb0, Bkb1; float Bvs[16];

    // prologue: tile 0 -> bank A
    Aka0 = *(const float4*)(kp);      Aka1 = *(const float4*)(kp + 4);
    Akb0 = *(const float4*)(kp + 32); Akb1 = *(const float4*)(kp + 36);
    #pragma unroll
    for (int dg = 0; dg < 4; ++dg)
        #pragma unroll
        for (int j = 0; j < 4; ++j)
            Avs[dg*4+j] = vp[j*512 + dg*16];

    __syncthreads();                  // Qs + dls ready (only pre-epilogue barrier)

// body computes tile t_ from bank C; if HASNEXT, first issues tile t_+1 into bank N
#define TILE_BODY(t_, MASKED, HASNEXT, C, N) do {                           \
        if (HASNEXT) {                                                      \
            kp += 32768; vp += 32768;                                       \
            N##ka0 = *(const float4*)(kp);                                  \
            N##ka1 = *(const float4*)(kp + 4);                              \
            N##kb0 = *(const float4*)(kp + 32);                             \
            N##kb1 = *(const float4*)(kp + 36);                             \
            _Pragma("unroll")                                               \
            for (int dg = 0; dg < 4; ++dg)                                  \
                _Pragma("unroll")                                           \
                for (int j = 0; j < 4; ++j)                                 \
                    N##vs[dg*4+j] = vp[j*512 + dg*16];                      \
        }                                                                   \
        /* K -> bf16 A-operand frags, scalar f2bs (proven numerics) */      \
        bf16x8 kf0_ = {f2bs(C##ka0.x),f2bs(C##ka0.y),f2bs(C##ka0.z),f2bs(C##ka0.w), \
                       f2bs(C##ka1.x),f2bs(C##ka1.y),f2bs(C##ka1.z),f2bs(C##ka1.w)}; \
        bf16x8 kf1_ = {f2bs(C##kb0.x),f2bs(C##kb0.y),f2bs(C##kb0.z),f2bs(C##kb0.w), \
                       f2bs(C##kb1.x),f2bs(C##kb1.y),f2bs(C##kb1.z),f2bs(C##kb1.w)}; \
        f32x4 sacc_[4];                                                     \
        __builtin_amdgcn_s_setprio(1);                                      \
        _Pragma("unroll")                                                   \
        for (int qg = 0; qg < 4; ++qg) {                                    \
            bf16x8 qa_ = *(const bf16x8*)(&Qs[(qg*2+0)*512 + lane*8]);      \
            bf16x8 qb_ = *(const bf16x8*)(&Qs[(qg*2+1)*512 + lane*8]);      \
            f32x4 z_ = (f32x4){0.f,0.f,0.f,0.f};                            \
            z_ = __builtin_amdgcn_mfma_f32_16x16x32_bf16(kf0_, qa_, z_, 0,0,0); \
            sacc_[qg] = __builtin_amdgcn_mfma_f32_16x16x32_bf16(kf1_, qb_, z_, 0,0,0); \
        }                                                                   \
        __builtin_amdgcn_s_setprio(0);                                      \
        if (MASKED) {                                                       \
            _Pragma("unroll")                                               \
            for (int qg = 0; qg < 4; ++qg)                                  \
                _Pragma("unroll")                                           \
                for (int r = 0; r < 4; ++r)                                 \
                    if (kq*16 + quad*4 + r > qg*16 + ln) sacc_[qg][r] = -1e30f; \
        }                                                                   \
        f32x4 dlv_ = *(const f32x4*)&dls[(t_)*64 + kq*16 + quad*4];         \
        bf16x4 pT_[4];                                                      \
        _Pragma("unroll")                                                   \
        for (int qg = 0; qg < 4; ++qg) {                                    \
            float p0_ = __builtin_amdgcn_exp2f(fmaf(sacc_[qg][0], st2, dlv_[0])); \
            float p1_ = __builtin_amdgcn_exp2f(fmaf(sacc_[qg][1], st2, dlv_[1])); \
            float p2_ = __builtin_amdgcn_exp2f(fmaf(sacc_[qg][2], st2, dlv_[2])); \
            float p3_ = __builtin_amdgcn_exp2f(fmaf(sacc_[qg][3], st2, dlv_[3])); \
            l_acc[qg] += (p0_ + p1_) + (p2_ + p3_);                         \
            pT_[qg] = (bf16x4){f2bs_rh(p0_), f2bs_rh(p1_),                  \
                               f2bs_rh(p2_), f2bs_rh(p3_)};                 \
        }                                                                   \
        /* V -> bf16 A-operand frags, scalar f2bs */                        \
        bf16x4 vf_[4];                                                      \
        _Pragma("unroll")                                                   \
        for (int dg = 0; dg < 4; ++dg)                                      \
            vf_[dg] = (bf16x4){f2bs(C##vs[dg*4+0]), f2bs(C##vs[dg*4+1]),    \
                               f2bs(C##vs[dg*4+2]), f2bs(C##vs[dg*4+3])};   \
        __builtin_amdgcn_s_setprio(1);                                      \
        _Pragma("unroll")                                                   \
        for (int dg = 0; dg < 4; ++dg)                                      \
            _Pragma("unroll")                                               \
            for (int qg = 0; qg < 4; ++qg)                                  \
                oacc[dg][qg] = __builtin_amdgcn_mfma_f32_16x16x16bf16_1k(   \
                    vf_[dg], pT_[qg], oacc[dg][qg], 0,0,0);                 \
        __builtin_amdgcn_s_setprio(0);                                      \
    } while (0)

    // unrolled x2 with bank alternation; masked diagonal tile last, no prefetch
    int t = 0;
    for (; t + 2 <= T - 1; t += 2) {
        TILE_BODY(t,     false, true, A, B);
        TILE_BODY(t + 1, false, true, B, A);
    }
    if (t < T - 1) {                  // leftover unmasked tile in A, loads into B
        TILE_BODY(t, false, true, A, B);
        TILE_BODY(T - 1, true, false, B, A);
    } else {
        TILE_BODY(T - 1, true, false, A, B);
    }

    // ---- epilogue: 4-way cross-kq reduction of O and l via LDS overlays ----
    float lq[4];
    #pragma unroll
    for (int qg = 0; qg < 4; ++qg) {
        float s = l_acc[qg];
        s += __shfl_xor(s, 16, 64);
        s += __shfl_xor(s, 32, 64);
        lq[qg] = s;                   // full-wave l for (qg, q=ln), replicated
    }
    float* KbF = &Ored[0][0];         // 16 KB wave-1 O, layout (dg*4+qg)*256+lane*4
    float* VbF = &Ored[1][0];         // 16 KB wave-3 O
    float* lred = dls;                // 256 f: [kq][qg][16 q]
    __syncthreads();                  // all loop reads of Qs/dls done

    if (lane < 16)
        #pragma unroll
        for (int qg = 0; qg < 4; ++qg) lred[kq*64 + qg*16 + ln] = lq[qg];
    if (kq == 1 || kq == 3) {
        float* dst = (kq == 1) ? KbF : VbF;
        #pragma unroll
        for (int dg = 0; dg < 4; ++dg)
            #pragma unroll
            for (int qg = 0; qg < 4; ++qg)
                *(f32x4*)(dst + (dg*4+qg)*256 + lane*4) = oacc[dg][qg];
    }
    __syncthreads();
    if (kq == 0 || kq == 2) {
        const float* srcp = (kq == 0) ? KbF : VbF;
        #pragma unroll
        for (int dg = 0; dg < 4; ++dg)
            #pragma unroll
            for (int qg = 0; qg < 4; ++qg) {
                f32x4 v = *(const f32x4*)(srcp + (dg*4+qg)*256 + lane*4);
                oacc[dg][qg][0] += v[0]; oacc[dg][qg][1] += v[1];
                oacc[dg][qg][2] += v[2]; oacc[dg][qg][3] += v[3];
            }
    }
    __syncthreads();
    if (kq == 2) {
        #pragma unroll
        for (int dg = 0; dg < 4; ++dg)
            #pragma unroll
            for (int qg = 0; qg < 4; ++qg)
                *(f32x4*)(KbF + (dg*4+qg)*256 + lane*4) = oacc[dg][qg];
    }
    __syncthreads();
    if (kq == 0) {
        float inv[4];
        #pragma unroll
        for (int qg = 0; qg < 4; ++qg)
            inv[qg] = 1.0f / (lred[qg*16 + ln] + lred[64 + qg*16 + ln]
                            + lred[128 + qg*16 + ln] + lred[192 + qg*16 + ln]);
        #pragma unroll
        for (int qg = 0; qg < 4; ++qg) {
            float* orow = out + (((size_t)b*Lsz + q0 + qg*16 + ln)*Hsz + h)*64;
            #pragma unroll
            for (int dg = 0; dg < 4; ++dg) {
                f32x4 v = *(const f32x4*)(KbF + (dg*4+qg)*256 + lane*4);
                float4 o = {(oacc[dg][qg][0] + v[0]) * inv[qg],
                            (oacc[dg][qg][1] + v[1]) * inv[qg],
                            (oacc[dg][qg][2] + v[2]) * inv[qg],
                            (oacc[dg][qg][3] + v[3]) * inv[qg]};
                *(float4*)(orow + dg*16 + quad*4) = o;
            }
        }
    }
#undef TILE_BODY
}

extern "C" void kernel_launch(void* const* d_in, const int* in_sizes, int n_in,
                              void* d_out, int out_size, void* d_ws, size_t ws_size,
                              hipStream_t stream) {
    (void)in_sizes; (void)n_in; (void)out_size; (void)d_ws; (void)ws_size;
    const float* q     = (const float*)d_in[0];
    const float* k     = (const float*)d_in[1];
    const float* v     = (const float*)d_in[2];
    const float* tau   = (const float*)d_in[3];
    const float* delta = (const float*)d_in[4];
    float* out = (float*)d_out;

    // single fused kernel: no prep pass, workspace untouched
    dsattn_fused<<<dim3(Bsz*Hsz, 32), dim3(256), 0, stream>>>(q, k, v, tau, delta, out);
}

// Round 10
// 124.689 us; speedup vs baseline: 2.8636x; 2.8636x over previous
//
#include <hip/hip_runtime.h>
#include <hip/hip_bf16.h>

#define Bsz 4
#define Lsz 2048
#define Hsz 8

typedef __attribute__((ext_vector_type(8)))  short bf16x8;
typedef __attribute__((ext_vector_type(4)))  float f32x4;
typedef __attribute__((ext_vector_type(16))) float f32x16;
typedef __attribute__((ext_vector_type(2)))  unsigned u32x2;

__device__ __forceinline__ short f2bs(float f) {   // RNE, prep/Q only
    union { float f; unsigned u; } v; v.f = f;
    unsigned r = v.u + 0x7FFFu + ((v.u >> 16) & 1u);
    return (short)(r >> 16);
}
__device__ __forceinline__ unsigned cvtpk(float lo, float hi) {
    unsigned r;
    asm("v_cvt_pk_bf16_f32 %0, %1, %2" : "=v"(r) : "v"(lo), "v"(hi));
    return r;
}

// async global->LDS, 16B per lane; LDS dest is wave-uniform base + lane*16
__device__ __forceinline__ void stage16(const short* g, short* l) {
    __builtin_amdgcn_global_load_lds(
        (const __attribute__((address_space(1))) unsigned int*)g,
        (__attribute__((address_space(3))) unsigned int*)l,
        16, 0, 0);
}

// ---------------- pre-pass: direct-load, no LDS, no barrier ----------------
// R2's prep (LDS transpose, 2048 blocks) ran ~40us for only 48MB of traffic -
// latency/launch bound. R10 prep: 1024 blocks (K AND V for one (bh,tile)),
// straight global->register->convert->store. Layout contract is BYTE-IDENTICAL
// to R2's prep (same f2bs, same chunk order), so R2's proven main is unchanged:
// K chunk c = kh*4+eb, lane(l31,hi): K[kh*32+l31][eb*16+hi*8+j]  (A-op 32x32x16)
// V chunk c = dh*4+kb, lane(l31,hi): V[kb*16+hi*8+j][dh*32+l31]  (V^T, A-op)
__global__ __launch_bounds__(256) void prep_kv(
    const float* __restrict__ ksrc, const float* __restrict__ vsrc,
    short* __restrict__ Kf, short* __restrict__ Vf)
{
    const int bid = blockIdx.x;          // (bh<<5) | tile
    const int tl = bid & 31, bh = bid >> 5;
    const int b = bh >> 3, h = bh & 7;
    const int tid = threadIdx.x;
    const int w = tid >> 6, lane = tid & 63;
    const int l31 = lane & 31, hi = lane >> 5;

    // two K chunks per wave: c = 2w, 2w+1 (lane reads 32B contiguous)
    #pragma unroll
    for (int cc = 0; cc < 2; ++cc) {
        const int c = w*2 + cc;          // 0..7
        const int kh = c >> 2, eb = c & 3;
        const float* gk = ksrc
            + (((size_t)b*Lsz + tl*64 + kh*32 + l31)*Hsz + h)*64 + eb*16 + hi*8;
        float4 a0 = *(const float4*)(gk);
        float4 a1 = *(const float4*)(gk + 4);
        bf16x8 o = {f2bs(a0.x),f2bs(a0.y),f2bs(a0.z),f2bs(a0.w),
                    f2bs(a1.x),f2bs(a1.y),f2bs(a1.z),f2bs(a1.w)};
        *(bf16x8*)(Kf + (size_t)bid*4096 + c*512 + lane*8) = o;
    }
    // two V chunks per wave: c = 2w, 2w+1 (8 dword loads, row stride 512 floats)
    #pragma unroll
    for (int cc = 0; cc < 2; ++cc) {
        const int c = w*2 + cc;          // 0..7
        const int dh = c >> 2, kb = c & 3;
        const float* gv = vsrc
            + (((size_t)b*Lsz + tl*64 + kb*16 + hi*8)*Hsz + h)*64 + dh*32 + l31;
        bf16x8 o = {f2bs(gv[0*512]), f2bs(gv[1*512]),
                    f2bs(gv[2*512]), f2bs(gv[3*512]),
                    f2bs(gv[4*512]), f2bs(gv[5*512]),
                    f2bs(gv[6*512]), f2bs(gv[7*512])};
        *(bf16x8*)(Vf + (size_t)bid*4096 + c*512 + lane*8) = o;
    }
}

// ---------------- main: S^T flash attention, 32x32x16 MFMA, 2x2 wave split ---------
// VERBATIM from the passing R2 kernel (best main measured: ~41us).
__global__ __launch_bounds__(256, 4) void dsattn_main(
    const float* __restrict__ q,
    const short* __restrict__ Kf,
    const short* __restrict__ Vf,
    const float* __restrict__ tau,
    const float* __restrict__ delta,
    float* __restrict__ out)
{
    __shared__ __align__(16) short Kb[2][4096];   // 16 KB dbuf (reused as Ored)
    __shared__ __align__(16) short Vb[2][4096];   // 16 KB dbuf (reused as lred)
    __shared__ float dls[Lsz];                    //  8 KB c2*delta[b][:]
    // total 40 KB -> 4 blocks/CU = 160 KB = full LDS

    const int tid  = threadIdx.x;
    const int wv   = tid >> 6;
    const int lane = tid & 63;
    const int l31  = lane & 31;
    const int hi   = lane >> 5;
    const int qh   = wv & 1;          // q-half of the 64-row block
    const int kh   = wv >> 1;         // key-half of each 64-key tile

    const int bh = blockIdx.x;
    const int b  = bh >> 3, h = bh & 7;
    const int j  = blockIdx.y, aj = j & 7, gj = j >> 3;
    const int qt = (gj == 0) ? 31 - 2*aj : (gj == 1) ? 30 - 2*aj
                 : (gj == 2) ? 2*aj + 1  : 2*aj;
    const int q0 = qt * 64;
    const int T  = qt + 1;            // 64-key tiles

    const float c2  = 0.125f * 1.44269504f;   // scale * log2(e)
    const float st2 = c2 * tau[b];

    const short* kt = Kf + (size_t)bh * (32*4096);
    const short* vt = Vf + (size_t)bh * (32*4096);

    // incremental staging pointer: waves 0,1 -> K chunks, 2,3 -> V chunks
    const short* gsrc = ((wv < 2) ? kt : vt) + (wv & 1)*2048 + lane*8;

#define STAGE(buf) do {                                                     \
        short* lb_ = (wv < 2 ? &Kb[(buf)][0] : &Vb[(buf)][0]) + (wv&1)*2048;\
        stage16(gsrc + 0*512, lb_ + 0*512);                                 \
        stage16(gsrc + 1*512, lb_ + 1*512);                                 \
        stage16(gsrc + 2*512, lb_ + 2*512);                                 \
        stage16(gsrc + 3*512, lb_ + 3*512);                                 \
        gsrc += 4096;                                                       \
    } while (0)

    STAGE(0);                         // tile 0 in flight first

    // stage c2*delta (256 thr x 8 floats)
    {
        const float* dsrc = delta + (size_t)b*Lsz + tid*8;
        float4 a = *(const float4*)(dsrc);
        float4 c = *(const float4*)(dsrc + 4);
        a.x*=c2; a.y*=c2; a.z*=c2; a.w*=c2;
        c.x*=c2; c.y*=c2; c.z*=c2; c.w*=c2;
        *(float4*)&dls[tid*8]     = a;
        *(float4*)&dls[tid*8 + 4] = c;
    }

    // Q fragments: B-operand 32x32x16 per 16-e block:
    // lane holds Q[q0+qh*32+l31][eb*16 + hi*8 + j], j=0..7
    bf16x8 qf[4];
    {
        const float* qrow = q + (((size_t)b*Lsz + q0 + qh*32 + l31)*Hsz + h)*64 + hi*8;
        #pragma unroll
        for (int eb = 0; eb < 4; ++eb) {
            float4 a0 = *(const float4*)(qrow + eb*16);
            float4 a1 = *(const float4*)(qrow + eb*16 + 4);
            qf[eb] = (bf16x8){f2bs(a0.x),f2bs(a0.y),f2bs(a0.z),f2bs(a0.w),
                              f2bs(a1.x),f2bs(a1.y),f2bs(a1.z),f2bs(a1.w)};
        }
    }

    f32x16 oacc0, oacc1;              // O^T partials: d 0..31 / 32..63, this k-half
    #pragma unroll
    for (int i = 0; i < 16; ++i) { oacc0[i] = 0.f; oacc1[i] = 0.f; }
    float l_acc = 0.f;

    __syncthreads();                  // tile 0 + dls staged (barrier drains vmcnt)

#define TILE_BODY(t_, MASKED) do {                                          \
        const int cur_ = (t_) & 1;                                          \
        const short* Kc_ = &Kb[cur_][0];                                    \
        const short* Vc_ = &Vb[cur_][0];                                    \
        const int k0_ = (t_)*64;                                            \
        f32x16 sacc;                                                        \
        _Pragma("unroll")                                                   \
        for (int i = 0; i < 16; ++i) sacc[i] = 0.f;                         \
        __builtin_amdgcn_s_setprio(1);                                      \
        _Pragma("unroll")                                                   \
        for (int eb = 0; eb < 4; ++eb) {                                    \
            bf16x8 kf_ = *(const bf16x8*)(Kc_ + (kh*4 + eb)*512 + lane*8);  \
            sacc = __builtin_amdgcn_mfma_f32_32x32x16_bf16(kf_, qf[eb], sacc, 0,0,0); \
        }                                                                   \
        __builtin_amdgcn_s_setprio(0);                                      \
        if (MASKED) {                                                       \
            const int qrw_ = qh*32 + l31;                                   \
            _Pragma("unroll")                                               \
            for (int g = 0; g < 4; ++g)                                     \
                _Pragma("unroll")                                           \
                for (int i = 0; i < 4; ++i)                                 \
                    if (kh*32 + 8*g + 4*hi + i > qrw_) sacc[g*4+i] = -1e30f;\
        }                                                                   \
        float p_[16];                                                       \
        _Pragma("unroll")                                                   \
        for (int g = 0; g < 4; ++g) {                                       \
            f32x4 dlv_ = *(const f32x4*)&dls[k0_ + kh*32 + g*8 + hi*4];     \
            _Pragma("unroll")                                               \
            for (int i = 0; i < 4; ++i)                                     \
                p_[g*4+i] = __builtin_amdgcn_exp2f(fmaf(sacc[g*4+i], st2, dlv_[i])); \
            l_acc += (p_[g*4]+p_[g*4+1]) + (p_[g*4+2]+p_[g*4+3]);           \
        }                                                                   \
        bf16x8 pf_[2];                                                      \
        _Pragma("unroll")                                                   \
        for (int kb = 0; kb < 2; ++kb) {                                    \
            unsigned a0_ = cvtpk(p_[kb*8+0], p_[kb*8+1]);                   \
            unsigned a1_ = cvtpk(p_[kb*8+2], p_[kb*8+3]);                   \
            unsigned b0_ = cvtpk(p_[kb*8+4], p_[kb*8+5]);                   \
            unsigned b1_ = cvtpk(p_[kb*8+6], p_[kb*8+7]);                   \
            u32x2 s0_ = __builtin_amdgcn_permlane32_swap(a0_, b0_, false, false); \
            u32x2 s1_ = __builtin_amdgcn_permlane32_swap(a1_, b1_, false, false); \
            union { unsigned u[4]; bf16x8 v; } pk_;                         \
            pk_.u[0] = s0_[0]; pk_.u[1] = s1_[0];                           \
            pk_.u[2] = s0_[1]; pk_.u[3] = s1_[1];                           \
            pf_[kb] = pk_.v;                                                \
        }                                                                   \
        __builtin_amdgcn_s_setprio(1);                                      \
        _Pragma("unroll")                                                   \
        for (int kb = 0; kb < 2; ++kb) {                                    \
            bf16x8 vf0_ = *(const bf16x8*)(Vc_ + (     kh*2 + kb)*512 + lane*8); \
            bf16x8 vf1_ = *(const bf16x8*)(Vc_ + (4 +  kh*2 + kb)*512 + lane*8); \
            oacc0 = __builtin_amdgcn_mfma_f32_32x32x16_bf16(vf0_, pf_[kb], oacc0, 0,0,0); \
            oacc1 = __builtin_amdgcn_mfma_f32_32x32x16_bf16(vf1_, pf_[kb], oacc1, 0,0,0); \
        }                                                                   \
        __builtin_amdgcn_s_setprio(0);                                      \
    } while (0)

    // maskless main loop over tiles 0..T-2
    for (int t = 0; t + 1 < T; ++t) {
        STAGE((t + 1) & 1);           // stream tile t+1 into the other buffer
        TILE_BODY(t, false);
        __syncthreads();              // staged t+1 complete + all reads of cur done
    }
    // diagonal tile T-1 (the only masked one)
    TILE_BODY(T - 1, true);

    // ---- cross-wave (kh) reduction via LDS, then normalize + store ----
    float lw = l_acc + __shfl_xor(l_acc, 32, 64);   // hi-half fold, per q=l31
    float* Ored = (float*)&Kb[0][0];  // 2*64*32 f32 = 16 KB
    float* lred = (float*)&Vb[0][0];  // 64 f32
    __syncthreads();                  // everyone done with Kb/Vb tile data

    if (kh == 1) {
        #pragma unroll
        for (int g = 0; g < 4; ++g)
            #pragma unroll
            for (int i = 0; i < 4; ++i) {
                const int d_ = 8*g + 4*hi + i;
                Ored[(qh*64 +      d_)*32 + l31] = oacc0[g*4+i];
                Ored[(qh*64 + 32 + d_)*32 + l31] = oacc1[g*4+i];
            }
        if (lane < 32) lred[qh*32 + l31] = lw;
    }
    __syncthreads();

    if (kh == 0) {
        const float invl = 1.0f / (lw + lred[qh*32 + l31]);
        float* orow = out + (((size_t)b*Lsz + q0 + qh*32 + l31)*Hsz + h)*64;
        #pragma unroll
        for (int g = 0; g < 4; ++g) {
            const int d_ = 8*g + 4*hi;
            float4 o0, o1;
            o0.x = (oacc0[g*4+0] + Ored[(qh*64 + d_ + 0)*32 + l31]) * invl;
            o0.y = (oacc0[g*4+1] + Ored[(qh*64 + d_ + 1)*32 + l31]) * invl;
            o0.z = (oacc0[g*4+2] + Ored[(qh*64 + d_ + 2)*32 + l31]) * invl;
            o0.w = (oacc0[g*4+3] + Ored[(qh*64 + d_ + 3)*32 + l31]) * invl;
            o1.x = (oacc1[g*4+0] + Ored[(qh*64 + 32 + d_ + 0)*32 + l31]) * invl;
            o1.y = (oacc1[g*4+1] + Ored[(qh*64 + 32 + d_ + 1)*32 + l31]) * invl;
            o1.z = (oacc1[g*4+2] + Ored[(qh*64 + 32 + d_ + 2)*32 + l31]) * invl;
            o1.w = (oacc1[g*4+3] + Ored[(qh*64 + 32 + d_ + 3)*32 + l31]) * invl;
            *(float4*)(orow + d_)      = o0;
            *(float4*)(orow + 32 + d_) = o1;
        }
    }
#undef STAGE
#undef TILE_BODY
}

extern "C" void kernel_launch(void* const* d_in, const int* in_sizes, int n_in,
                              void* d_out, int out_size, void* d_ws, size_t ws_size,
                              hipStream_t stream) {
    (void)in_sizes; (void)n_in; (void)out_size; (void)ws_size;
    const float* q     = (const float*)d_in[0];
    const float* k     = (const float*)d_in[1];
    const float* v     = (const float*)d_in[2];
    const float* tau   = (const float*)d_in[3];
    const float* delta = (const float*)d_in[4];
    float* out = (float*)d_out;

    short* Kf = (short*)d_ws;                          // 8 MiB bf16 fragments
    short* Vf = (short*)d_ws + (size_t)(4*1024*1024);  // next 8 MiB

    prep_kv<<<dim3(Bsz*Hsz*32), dim3(256), 0, stream>>>(k, v, Kf, Vf);
    dsattn_main<<<dim3(Bsz*Hsz, 32), dim3(256), 0, stream>>>(q, Kf, Vf, tau, delta, out);
}